// Round 1
// baseline (341.256 us; speedup 1.0000x reference)
//
#include <hip/hip_runtime.h>
#include <math.h>

#define B_ 2
#define P_ 200000
#define Q_ 100
#define NUMC 1

// ws layout: [0..B_*Q_) int nonempty flags, [256..256+B_*Q_) int seg table
#define WS_NONEMPTY_OFF 0
#define WS_SEG_OFF      256   // in ints

// d_out layout (float): [0, B*P) sem | [B*P, 2*B*P) ins | [2*B*P, 3*B*P) max_confs
// pass1 stashes mid (as float, -1 if invalid) in the ins slot; pass3 finalizes it.

__global__ __launch_bounds__(256) void pano_pass1(
    const float* __restrict__ logits,        // [B,Q,2]
    const float* __restrict__ masks,         // [B,P,Q]
    const unsigned char* __restrict__ pad,   // [B,P] bool
    float* __restrict__ out,                 // [3,B,P]
    int* __restrict__ nonempty)              // [B,Q] in ws (pre-zeroed)
{
    const int b = blockIdx.y;
    const int p = blockIdx.x * blockDim.x + threadIdx.x;

    __shared__ float s_score[Q_];
    __shared__ int   s_keep[Q_];
    __shared__ int   s_label[Q_];
    __shared__ int   s_flag[Q_];

    if (threadIdx.x < Q_) {
        float l0 = logits[(b * Q_ + threadIdx.x) * 2 + 0];
        float l1 = logits[(b * Q_ + threadIdx.x) * 2 + 1];
        int lab = (l1 > l0) ? 1 : 0;          // jnp.argmax: first index on tie
        s_label[threadIdx.x] = lab;
        s_keep[threadIdx.x]  = (lab != NUMC) ? 1 : 0;
        s_score[threadIdx.x] = fmaxf(l0, l1);
        s_flag[threadIdx.x]  = 0;
    }
    __syncthreads();

    if (p < P_) {
        const float4* row =
            reinterpret_cast<const float4*>(masks + ((size_t)b * P_ + p) * Q_);

        float M = -INFINITY;   // running max of masked prob values (kept only)
        float S = 0.0f;        // running sum of exp(val - M)
        float mbest = 0.0f;    // sigmoid at argmax
        int   best = -1;       // argmax query index (full query space)

        for (int j = 0; j < Q_ / 4; ++j) {
            float4 v4 = row[j];
            float xv[4] = {v4.x, v4.y, v4.z, v4.w};
            #pragma unroll
            for (int e = 0; e < 4; ++e) {
                int q = 4 * j + e;
                if (s_keep[q]) {
                    // accurate sigmoid: argmax must match fp32 reference ordering
                    float m   = 1.0f / (1.0f + expf(-xv[e]));
                    float val = s_score[q] * m;
                    if (val > M) {           // strict: keeps FIRST max (jnp tie rule)
                        S = S * __expf(M - val) + 1.0f;  // S*0+1 on first iter (M=-inf)
                        M = val; best = q; mbest = m;
                    } else {
                        S += __expf(val - M);
                    }
                }
            }
        }

        bool valid = (best >= 0) && (mbest >= 1e-3f) &&
                     (pad[(size_t)b * P_ + p] == 0);
        if (!valid) best = -1;

        size_t o = (size_t)b * P_ + p;
        // sem: valid ? labels[mid] : 0  (labels[mid]==0 whenever valid w/ NUMC=1)
        out[o] = (best >= 0) ? (float)s_label[best] : 0.0f;
        // ins slot: stash mid for pass3 (exactly representable: -1..99)
        out[(size_t)B_ * P_ + o] = (float)best;
        // max_confs = softmax max = 1/sum(exp(val - M)) over kept queries
        out[2 * (size_t)B_ * P_ + o] = 1.0f / S;

        if (best >= 0) s_flag[best] = 1;   // benign race, all write 1
    }
    __syncthreads();

    if (threadIdx.x < Q_ && s_flag[threadIdx.x])
        atomicOr(&nonempty[b * Q_ + threadIdx.x], 1);
}

__global__ void pano_pass2(const int* __restrict__ nonempty,
                           int* __restrict__ seg)
{
    int b = threadIdx.x;
    if (b < B_) {
        int c = 0;
        for (int q = 0; q < Q_; ++q) {
            c += (nonempty[b * Q_ + q] != 0) ? 1 : 0;  // inclusive cumsum
            seg[b * Q_ + q] = c;
        }
    }
}

__global__ __launch_bounds__(256) void pano_pass3(
    const int* __restrict__ seg,
    float* __restrict__ out)
{
    const int b = blockIdx.y;
    const int p = blockIdx.x * blockDim.x + threadIdx.x;
    if (p >= P_) return;
    size_t o = (size_t)B_ * P_ + (size_t)b * P_ + p;
    int mid = (int)out[o];                 // stashed by pass1
    out[o] = (mid >= 0) ? (float)seg[b * Q_ + mid] : 0.0f;
}

extern "C" void kernel_launch(void* const* d_in, const int* in_sizes, int n_in,
                              void* d_out, int out_size, void* d_ws, size_t ws_size,
                              hipStream_t stream) {
    const float* logits = (const float*)d_in[0];
    const float* masks  = (const float*)d_in[1];
    const unsigned char* pad = (const unsigned char*)d_in[2];
    float* out = (float*)d_out;
    int* nonempty = (int*)d_ws + WS_NONEMPTY_OFF;
    int* seg      = (int*)d_ws + WS_SEG_OFF;

    // zero the nonempty flags (ws is poisoned 0xAA before every timed call)
    hipMemsetAsync(d_ws, 0, (WS_SEG_OFF + B_ * Q_) * sizeof(int), stream);

    dim3 block(256);
    dim3 grid1((P_ + 255) / 256, B_);
    pano_pass1<<<grid1, block, 0, stream>>>(logits, masks, pad, out, nonempty);
    pano_pass2<<<1, 64, 0, stream>>>(nonempty, seg);
    pano_pass3<<<grid1, block, 0, stream>>>(seg, out);
}

// Round 2
// 308.362 us; speedup vs baseline: 1.1067x; 1.1067x over previous
//
#include <hip/hip_runtime.h>
#include <math.h>

#define B_ 2
#define P_ 200000
#define Q_ 100
#define NQ4 25          // float4s per row (Q_/4)

// ws layout: [0 .. B_*Q_) int nonempty flags (memset to 0 each call)
// d_out (float): [0,B*P) sem | [B*P,2BP) ins | [2BP,3BP) max_confs
// pass1 stashes mid (float, -1 if invalid) in the ins slot; pass3 finalizes.

// 4 lanes per row, 16 rows per wave, 64 rows per 256-thread block.
// P_ = 200000 = 3125 * 64 exactly -> no row bounds check needed.
__global__ __launch_bounds__(256) void pano_pass1(
    const float* __restrict__ logits,        // [B,Q,2]
    const float* __restrict__ masks,         // [B,P,Q]
    const unsigned char* __restrict__ pad,   // [B,P]
    float* __restrict__ out,                 // [3,B,P]
    int* __restrict__ nonempty)              // [B,Q] ws, pre-zeroed
{
    const int b   = blockIdx.y;
    const int tid = threadIdx.x;

    __shared__ float s_mscore[Q_];   // keep ? max(l0,l1) : -1e30 (mask sentinel)
    __shared__ int   s_flag[Q_];

    if (tid < Q_) {
        float l0 = logits[(b * Q_ + tid) * 2 + 0];
        float l1 = logits[(b * Q_ + tid) * 2 + 1];
        // keep iff argmax==0 iff !(l1>l0)  (jnp.argmax first-index tie rule)
        s_mscore[tid] = (l1 > l0) ? -1e30f : fmaxf(l0, l1);
        s_flag[tid]   = 0;
    }
    __syncthreads();

    const int wave = tid >> 6;          // 0..3
    const int wl   = tid & 63;
    const int g    = wl >> 2;           // row group within wave, 0..15
    const int l    = wl & 3;            // lane within group
    const int p    = blockIdx.x * 64 + wave * 16 + g;

    const float* row = masks + ((size_t)b * P_ + p) * Q_;

    // online softmax over masked vals: M=max, S=sum exp(val-M), best=argmax
    float M = -3e38f, S = 0.0f, mbest = 0.0f;
    int   best = -1;

    for (int k = 0; k < 7; ++k) {
        int f = k * 4 + l;              // float4 index within row
        if (f < NQ4) {
            float4 v4 = *reinterpret_cast<const float4*>(row + f * 4);
            float xv[4] = {v4.x, v4.y, v4.z, v4.w};
            #pragma unroll
            for (int e = 0; e < 4; ++e) {
                int q = f * 4 + e;
                // identical expression to the passing R1 kernel: argmax must
                // track the reference's fp32 sigmoid ordering bit-closely
                float m   = 1.0f / (1.0f + expf(-xv[e]));
                float val = s_mscore[q] * m;   // masked: ~-1e28 .. -1e30
                if (val > M) {                 // strict: first-max tie rule
                    S = S * __expf(M - val) + 1.0f;  // underflows to 0 on sentinel
                    M = val; best = q; mbest = m;
                } else {
                    S += __expf(val - M);      // masked deltas underflow to 0
                }
            }
        }
    }

    // merge the 4 lanes' states (butterfly xor 1,2). On M tie take smaller
    // query index (= earlier in jnp.argmax order); unsigned cast makes -1 lose.
    #pragma unroll
    for (int off = 1; off <= 2; off <<= 1) {
        float Mo = __shfl_xor(M, off, 64);
        float So = __shfl_xor(S, off, 64);
        float mo = __shfl_xor(mbest, off, 64);
        int   bo = __shfl_xor(best, off, 64);
        bool take = (Mo > M) || (Mo == M && (unsigned)bo < (unsigned)best);
        if (take) {
            S = So + S * __expf(M - Mo);
            M = Mo; best = bo; mbest = mo;
        } else {
            S = S + So * __expf(Mo - M);
        }
    }

    bool valid = (best >= 0) && (s_mscore[best] > -1e29f) &&  // keep[mid]
                 (mbest >= 1e-3f) &&
                 (pad[(size_t)b * P_ + p] == 0);

    float conf = 1.0f / S;                       // softmax max prob
    float insf = valid ? (float)best : -1.0f;    // stash mid for pass3

    if (l == 0 && valid) s_flag[best] = 1;       // benign race, all write 1

    // compact: lane t<16 gathers row t's result from lane 4t -> coalesced store
    int   src    = (wl & 15) * 4;
    float conf_g = __shfl(conf, src, 64);
    float insf_g = __shfl(insf, src, 64);
    if (wl < 16) {
        int prow = blockIdx.x * 64 + wave * 16 + wl;
        size_t o = (size_t)b * P_ + prow;
        out[o]                       = 0.0f;     // sem: labels[mid]==0 whenever valid (NUM_CLASSES=1)
        out[(size_t)B_ * P_ + o]     = insf_g;
        out[2 * (size_t)B_ * P_ + o] = conf_g;
    }

    __syncthreads();
    if (tid < Q_ && s_flag[tid])
        atomicOr(&nonempty[b * Q_ + tid], 1);
}

// finalize ins: per-block redundant 100-entry cumsum of nonempty (L2-hot),
// then ins = mid>=0 ? seg[mid] : 0
__global__ __launch_bounds__(256) void pano_pass3(
    const int* __restrict__ nonempty,
    float* __restrict__ out)
{
    const int b   = blockIdx.y;
    const int tid = threadIdx.x;
    __shared__ int s_seg[Q_];

    if (tid < Q_) s_seg[tid] = (nonempty[b * Q_ + tid] != 0) ? 1 : 0;
    __syncthreads();
    if (tid == 0) {
        int c = 0;
        #pragma unroll
        for (int q = 0; q < Q_; ++q) { c += s_seg[q]; s_seg[q] = c; }
    }
    __syncthreads();

    int p = blockIdx.x * blockDim.x + tid;
    if (p < P_) {
        size_t o = (size_t)B_ * P_ + (size_t)b * P_ + p;
        float f = out[o];
        out[o] = (f >= 0.0f) ? (float)s_seg[(int)f] : 0.0f;
    }
}

extern "C" void kernel_launch(void* const* d_in, const int* in_sizes, int n_in,
                              void* d_out, int out_size, void* d_ws, size_t ws_size,
                              hipStream_t stream) {
    const float* logits = (const float*)d_in[0];
    const float* masks  = (const float*)d_in[1];
    const unsigned char* pad = (const unsigned char*)d_in[2];
    float* out    = (float*)d_out;
    int* nonempty = (int*)d_ws;

    hipMemsetAsync(d_ws, 0, B_ * Q_ * sizeof(int), stream);

    dim3 block(256);
    dim3 grid1(P_ / 64, B_);                    // 3125 x 2
    pano_pass1<<<grid1, block, 0, stream>>>(logits, masks, pad, out, nonempty);
    dim3 grid3((P_ + 255) / 256, B_);           // 782 x 2
    pano_pass3<<<grid3, block, 0, stream>>>(nonempty, out);
}

// Round 3
// 300.494 us; speedup vs baseline: 1.1357x; 1.0262x over previous
//
#include <hip/hip_runtime.h>
#include <math.h>

#define B_ 2
#define P_ 200000
#define Q_ 100

// ws byte layout (all rewritten by prep every call; ws is poisoned 0xAA):
//   [0,    800)  int   nonempty[B_*Q_]   (zeroed by prep)
//   [1024, 1032) int   nk[B_]
//   [2048, 3648) float2 kp[B_][Q_]       (score, (float)q) kept queries, q ascending
//
// d_out (float): [0,B*P) sem | [B*P,2BP) ins | [2BP,3BP) max_confs
// pass1 stashes mid (float, -1 if invalid) in ins slot; pass3 finalizes.

__global__ void pano_prep(const float* __restrict__ logits,
                          int* __restrict__ flags,
                          int* __restrict__ nk,
                          float2* __restrict__ kp)
{
    const int b = blockIdx.x;
    const int tid = threadIdx.x;
    __shared__ float s_sc[Q_];
    __shared__ int   s_keep[Q_];
    if (tid < Q_) {
        float l0 = logits[(b * Q_ + tid) * 2 + 0];
        float l1 = logits[(b * Q_ + tid) * 2 + 1];
        s_keep[tid] = (l1 > l0) ? 0 : 1;     // keep iff argmax==0 (first-index tie)
        s_sc[tid]   = fmaxf(l0, l1);
        flags[b * Q_ + tid] = 0;             // zero ws flags (replaces memset)
    }
    __syncthreads();
    if (tid == 0) {
        int n = 0;
        for (int q = 0; q < Q_; ++q)
            if (s_keep[q]) { kp[b * Q_ + n] = make_float2(s_sc[q], (float)q); ++n; }
        nk[b] = n;
    }
}

// 4 lanes per row, 16 rows/wave, 64 rows per 256-thread block. P_=3125*64.
__global__ __launch_bounds__(256) void pano_pass1(
    const float* __restrict__ masks,         // [B,P,Q]
    const unsigned char* __restrict__ pad,   // [B,P]
    float* __restrict__ out,                 // [3,B,P]
    const int* __restrict__ nk,
    const float2* __restrict__ kp,
    int* __restrict__ flags)
{
    const int b   = blockIdx.y;
    const int tid = threadIdx.x;

    __shared__ float  s_x[64 * Q_];          // staged mask rows (25.6 KB)
    __shared__ float2 s_kp[Q_];
    __shared__ int    s_flag[Q_];
    __shared__ int    s_nk;

    if (tid < Q_) { s_kp[tid] = kp[b * Q_ + tid]; s_flag[tid] = 0; }
    if (tid == 0) s_nk = nk[b];

    const int wave = tid >> 6;
    const int wl   = tid & 63;
    const int g    = wl >> 2;                // row group in wave
    const int l    = wl & 3;                 // lane in group
    const int r    = wave * 16 + g;          // local row 0..63
    const int p    = blockIdx.x * 64 + r;

    const float4* grow =
        reinterpret_cast<const float4*>(masks + ((size_t)b * P_ + p) * Q_);
    float* lrow = s_x + r * Q_;

    // stage: coalesced float4 loads -> LDS (cross-lane consumers => barrier)
    #pragma unroll
    for (int k = 0; k < 7; ++k) {
        int f = k * 4 + l;
        if (f < 25) {
            float4 v = grow[f];
            *reinterpret_cast<float4*>(lrow + f * 4) = v;
        }
    }
    __syncthreads();

    const int knk = s_nk;                    // block-uniform
    const int nkk = (knk + 3) >> 2;

    float S0 = 0.0f;
    float val_b = -INFINITY, m_b = 0.0f;
    int   q_b = -1;

    for (int jj = 0; jj < nkk; ++jj) {
        int jx = jj * 4 + l;
        int jc = min(jx, knk - 1);
        float2 kpj = s_kp[jc];
        bool real = jx < knk;
        float x = lrow[(int)kpj.y];
        // EXACT same expression chain as the validated R2 kernel (np-matching
        // rounding): m = 1/(1+expf(-x)) IEEE div, val = score*m
        float e = expf(-x);
        float m = 1.0f / (1.0f + e);
        float val = real ? (kpj.x * m) : -INFINITY;   // ghost never wins / adds 0
        S0 += __expf(val);                            // no rescale chain: vals ~O(4)
        bool t = val > val_b;                         // strict: first-max tie rule
        val_b = t ? val : val_b;
        m_b   = t ? m   : m_b;
        q_b   = t ? (int)kpj.y : q_b;
    }

    // merge 4 lanes (xor 1,2); M tie -> smaller q (unsigned: -1 loses)
    #pragma unroll
    for (int off = 1; off <= 2; off <<= 1) {
        float So = __shfl_xor(S0, off, 64);
        float vo = __shfl_xor(val_b, off, 64);
        float mo = __shfl_xor(m_b, off, 64);
        int   qo = __shfl_xor(q_b, off, 64);
        S0 += So;
        bool t = (vo > val_b) || (vo == val_b && (unsigned)qo < (unsigned)q_b);
        val_b = t ? vo : val_b;
        m_b   = t ? mo : m_b;
        q_b   = t ? qo : q_b;
    }

    bool valid = (q_b >= 0) && (m_b >= 1e-3f) &&
                 (pad[(size_t)b * P_ + p] == 0);

    float conf = __expf(val_b) * __builtin_amdgcn_rcpf(S0);  // 2% tol: rcp fine
    float insf = valid ? (float)q_b : -1.0f;

    if (l == 0 && valid) s_flag[q_b] = 1;    // benign race, all write 1

    // compact stores: lane t<16 gathers row t's result from lane 4t
    int   src    = (wl & 15) * 4;
    float conf_g = __shfl(conf, src, 64);
    float insf_g = __shfl(insf, src, 64);
    if (wl < 16) {
        int prow = blockIdx.x * 64 + wave * 16 + wl;
        size_t o = (size_t)b * P_ + prow;
        out[o]                       = 0.0f;  // sem: labels[mid]==0 whenever valid
        out[(size_t)B_ * P_ + o]     = insf_g;
        out[2 * (size_t)B_ * P_ + o] = conf_g;
    }

    __syncthreads();
    if (tid < Q_ && s_flag[tid])
        atomicOr(&flags[b * Q_ + tid], 1);
}

__global__ __launch_bounds__(256) void pano_pass3(
    const int* __restrict__ flags,
    float* __restrict__ out)
{
    const int b   = blockIdx.y;
    const int tid = threadIdx.x;
    __shared__ int s_seg[Q_];

    if (tid < Q_) s_seg[tid] = (flags[b * Q_ + tid] != 0) ? 1 : 0;
    __syncthreads();
    if (tid == 0) {
        int c = 0;
        #pragma unroll
        for (int q = 0; q < Q_; ++q) { c += s_seg[q]; s_seg[q] = c; }
    }
    __syncthreads();

    int p = blockIdx.x * blockDim.x + tid;
    if (p < P_) {
        size_t o = (size_t)B_ * P_ + (size_t)b * P_ + p;
        float f = out[o];
        out[o] = (f >= 0.0f) ? (float)s_seg[(int)f] : 0.0f;
    }
}

extern "C" void kernel_launch(void* const* d_in, const int* in_sizes, int n_in,
                              void* d_out, int out_size, void* d_ws, size_t ws_size,
                              hipStream_t stream) {
    const float* logits = (const float*)d_in[0];
    const float* masks  = (const float*)d_in[1];
    const unsigned char* pad = (const unsigned char*)d_in[2];
    float* out = (float*)d_out;

    int*    flags = (int*)d_ws;
    int*    nkp   = (int*)((char*)d_ws + 1024);
    float2* kp    = (float2*)((char*)d_ws + 2048);

    pano_prep<<<dim3(B_), dim3(128), 0, stream>>>(logits, flags, nkp, kp);

    dim3 block(256);
    dim3 grid1(P_ / 64, B_);                 // 3125 x 2
    pano_pass1<<<grid1, block, 0, stream>>>(masks, pad, out, nkp, kp, flags);
    dim3 grid3((P_ + 255) / 256, B_);        // 782 x 2
    pano_pass3<<<grid3, block, 0, stream>>>(flags, out);
}

// Round 4
// 295.061 us; speedup vs baseline: 1.1566x; 1.0184x over previous
//
#include <hip/hip_runtime.h>
#include <math.h>

#define B_ 2
#define P_ 200000
#define Q_ 100

// ws byte layout (rewritten by prep each call):
//   [0,    800)  int   flags[B_*Q_]  (zeroed by prep)
//   [1024, 1824) float msc[B_*Q_]    keep ? max(l0,l1) : -1e30
//
// d_out (float): [0,B*P) sem | [B*P,2BP) ins | [2BP,3BP) max_confs
// pass1 stashes mid (float, -1 invalid) in ins slot; pass3 finalizes.

__global__ void pano_prep(const float* __restrict__ logits,
                          int* __restrict__ flags,
                          float* __restrict__ msc)
{
    const int b = blockIdx.x, tid = threadIdx.x;
    if (tid < Q_) {
        float l0 = logits[(b * Q_ + tid) * 2 + 0];
        float l1 = logits[(b * Q_ + tid) * 2 + 1];
        // keep iff argmax==0 iff !(l1>l0) (jnp first-index tie rule)
        msc[b * Q_ + tid]   = (l1 > l0) ? -1e30f : fmaxf(l0, l1);
        flags[b * Q_ + tid] = 0;
    }
}

// 4 lanes/row, 16 rows/wave, 64 rows per 256-thread block. P_ = 3125*64.
__global__ __launch_bounds__(256) void pano_pass1(
    const float* __restrict__ masks,         // [B,P,Q]
    const unsigned char* __restrict__ pad,   // [B,P]
    float* __restrict__ out,                 // [3,B,P]
    const float* __restrict__ msc,           // [B,Q] ws
    int* __restrict__ flags)                 // [B,Q] ws
{
    const int b = blockIdx.y, tid = threadIdx.x;
    __shared__ float s_msc[Q_];
    __shared__ int   s_flag[Q_];
    if (tid < Q_) { s_msc[tid] = msc[b * Q_ + tid]; s_flag[tid] = 0; }
    __syncthreads();

    const int wave = tid >> 6, wl = tid & 63;
    const int g = wl >> 2, l = wl & 3;
    const int p = blockIdx.x * 64 + wave * 16 + g;

    const float* rowp = masks + ((size_t)b * P_ + p) * Q_;
    const float4* grow = reinterpret_cast<const float4*>(rowp);

    // 7 independent 16B loads per lane -> high MLP
    float4 v[7];
    #pragma unroll
    for (int k = 0; k < 6; ++k) v[k] = grow[k * 4 + l];
    v[6] = grow[24];                 // same addr all 4 lanes; only l==0 consumes

    float S0 = 0.0f;
    float v1 = -INFINITY, v2 = -INFINITY, m1 = 0.0f;
    int   q1 = -1;

    #pragma unroll
    for (int k = 0; k < 7; ++k) {
        const bool act = (k < 6) || (l == 0);
        const int  qb  = (k < 6) ? (16 * k + 4 * l) : 96;
        float xv[4] = {v[k].x, v[k].y, v[k].z, v[k].w};
        #pragma unroll
        for (int e = 0; e < 4; ++e) {
            int q = qb + e;
            // FAST path: v_exp + v_rcp sigmoid (error ~1e-6 rel)
            float m   = __builtin_amdgcn_rcpf(1.0f + __expf(-xv[e]));
            float val = act ? s_msc[q] * m : -INFINITY;  // ghost: exp->0, never wins
            S0 += __expf(val);                           // vals bounded ~[0,4]: no rescale
            bool t = val > v1;                           // strict: first-max tie rule
            v2 = t ? v1 : fmaxf(v2, val);
            v1 = t ? val : v1;
            m1 = t ? m   : m1;
            q1 = t ? q   : q1;
        }
    }

    // merge 4 lanes (xor 1,2); v1 tie -> smaller q (unsigned: -1 loses)
    #pragma unroll
    for (int off = 1; off <= 2; off <<= 1) {
        float So  = __shfl_xor(S0, off, 64);
        float v1o = __shfl_xor(v1, off, 64);
        float v2o = __shfl_xor(v2, off, 64);
        float m1o = __shfl_xor(m1, off, 64);
        int   q1o = __shfl_xor(q1, off, 64);
        S0 += So;
        bool t = (v1o > v1) || (v1o == v1 && (unsigned)q1o < (unsigned)q1);
        v2 = fmaxf(fminf(v1, v1o), fmaxf(v2, v2o));      // 2nd max of union
        v1 = t ? v1o : v1;
        m1 = t ? m1o : m1;
        q1 = t ? q1o : q1;
    }

    // EXACT fallback when fast top-2 gap can't certify the argmax (~0.06% rows):
    // bit-identical chain to the validated R2 kernel (expf + IEEE div).
    if (l == 0 && (v1 - v2) < 5e-5f) {
        float bv = -INFINITY, bm = 0.0f; int bq = -1;
        for (int q = 0; q < Q_; ++q) {
            float x = rowp[q];                 // L1/L2 hot
            float e = expf(-x);
            float m = 1.0f / (1.0f + e);
            float vv = s_msc[q] * m;
            if (vv > bv) { bv = vv; bq = q; bm = m; }
        }
        q1 = bq; m1 = bm;                      // v1/S0 keep fast values (2% tol)
    }

    bool valid = (q1 >= 0) && (s_msc[q1] > -1e29f) &&     // keep[mid]
                 (m1 >= 1e-3f) &&
                 (pad[(size_t)b * P_ + p] == 0);

    float conf = __expf(v1) * __builtin_amdgcn_rcpf(S0);  // 2% tol
    float insf = valid ? (float)q1 : -1.0f;
    if (l == 0 && valid) s_flag[q1] = 1;                  // benign race

    // compact stores: lane t<16 gathers row t's result from its leader lane 4t
    int   src    = (wl & 15) * 4;
    float conf_g = __shfl(conf, src, 64);
    float insf_g = __shfl(insf, src, 64);
    if (wl < 16) {
        int prow = blockIdx.x * 64 + wave * 16 + wl;
        size_t o = (size_t)b * P_ + prow;
        out[o]                       = 0.0f;   // sem: labels[mid]==0 whenever valid
        out[(size_t)B_ * P_ + o]     = insf_g;
        out[2 * (size_t)B_ * P_ + o] = conf_g;
    }

    __syncthreads();
    if (tid < Q_ && s_flag[tid])
        atomicOr(&flags[b * Q_ + tid], 1);
}

__global__ __launch_bounds__(256) void pano_pass3(
    const int* __restrict__ flags,
    float* __restrict__ out)
{
    const int b = blockIdx.y, tid = threadIdx.x;
    __shared__ int s_seg[Q_];

    if (tid < Q_) s_seg[tid] = (flags[b * Q_ + tid] != 0) ? 1 : 0;
    __syncthreads();
    if (tid == 0) {
        int c = 0;
        #pragma unroll
        for (int q = 0; q < Q_; ++q) { c += s_seg[q]; s_seg[q] = c; }
    }
    __syncthreads();

    int p = blockIdx.x * blockDim.x + tid;
    if (p < P_) {
        size_t o = (size_t)B_ * P_ + (size_t)b * P_ + p;
        float f = out[o];
        out[o] = (f >= 0.0f) ? (float)s_seg[(int)f] : 0.0f;
    }
}

extern "C" void kernel_launch(void* const* d_in, const int* in_sizes, int n_in,
                              void* d_out, int out_size, void* d_ws, size_t ws_size,
                              hipStream_t stream) {
    const float* logits = (const float*)d_in[0];
    const float* masks  = (const float*)d_in[1];
    const unsigned char* pad = (const unsigned char*)d_in[2];
    float* out = (float*)d_out;

    int*   flags = (int*)d_ws;
    float* mscp  = (float*)((char*)d_ws + 1024);

    pano_prep<<<dim3(B_), dim3(128), 0, stream>>>(logits, flags, mscp);

    dim3 block(256);
    pano_pass1<<<dim3(P_ / 64, B_), block, 0, stream>>>(masks, pad, out, mscp, flags);
    pano_pass3<<<dim3((P_ + 255) / 256, B_), block, 0, stream>>>(flags, out);
}

// Round 5
// 245.108 us; speedup vs baseline: 1.3923x; 1.2038x over previous
//
#include <hip/hip_runtime.h>
#include <math.h>

#define B_   2
#define P_   200000
#define Q_   100
#define NREP 64          // flag-table replicas per batch (decontend atomics)

// ws byte layout:
//   [0, 51200)        int   flags[B_][NREP][Q_]   (zeroed via memsetAsync)
//   [52224, 53024)    float msc[B_*Q_]            (written by prep)
//   [53248, 54048)    int   seg[B_*Q_]            (written by pass2)
//
// d_out (float): [0,B*P) sem | [B*P,2BP) ins | [2BP,3BP) max_confs
// pass1 stashes mid (float, -1 invalid) in ins slot; pass3 finalizes.

__global__ void pano_prep(const float* __restrict__ logits,
                          float* __restrict__ msc)
{
    const int b = blockIdx.x, tid = threadIdx.x;
    if (tid < Q_) {
        float l0 = logits[(b * Q_ + tid) * 2 + 0];
        float l1 = logits[(b * Q_ + tid) * 2 + 1];
        // keep iff argmax==0 iff !(l1>l0) (jnp first-index tie rule)
        msc[b * Q_ + tid] = (l1 > l0) ? -1e30f : fmaxf(l0, l1);
    }
}

// 4 lanes/row, 16 rows/wave, 64 rows per 256-thread block. P_ = 3125*64.
__global__ __launch_bounds__(256) void pano_pass1(
    const float* __restrict__ masks,         // [B,P,Q]
    const unsigned char* __restrict__ pad,   // [B,P]
    float* __restrict__ out,                 // [3,B,P]
    const float* __restrict__ msc,           // [B,Q] ws
    int* __restrict__ flags)                 // [B][NREP][Q_] ws
{
    const int b = blockIdx.y, tid = threadIdx.x;
    __shared__ float s_msc[Q_];
    __shared__ int   s_flag[Q_];
    if (tid < Q_) { s_msc[tid] = msc[b * Q_ + tid]; s_flag[tid] = 0; }
    __syncthreads();

    const int wave = tid >> 6, wl = tid & 63;
    const int g = wl >> 2, l = wl & 3;
    const int p = blockIdx.x * 64 + wave * 16 + g;

    const float* rowp = masks + ((size_t)b * P_ + p) * Q_;
    const float4* grow = reinterpret_cast<const float4*>(rowp);

    // 7 independent 16B loads per lane -> high MLP
    float4 v[7];
    #pragma unroll
    for (int k = 0; k < 6; ++k) v[k] = grow[k * 4 + l];
    v[6] = grow[24];                 // same addr all 4 lanes; only l==0 consumes

    float S0 = 0.0f;
    float v1 = -INFINITY, v2 = -INFINITY, m1 = 0.0f;
    int   q1 = -1;

    #pragma unroll
    for (int k = 0; k < 7; ++k) {
        const bool act = (k < 6) || (l == 0);
        const int  qb  = (k < 6) ? (16 * k + 4 * l) : 96;
        float xv[4] = {v[k].x, v[k].y, v[k].z, v[k].w};
        #pragma unroll
        for (int e = 0; e < 4; ++e) {
            int q = qb + e;
            // FAST path: v_exp + v_rcp sigmoid (error ~1e-6 rel)
            float m   = __builtin_amdgcn_rcpf(1.0f + __expf(-xv[e]));
            float val = act ? s_msc[q] * m : -INFINITY;  // ghost: exp->0, never wins
            S0 += __expf(val);                           // vals bounded ~[0,4]
            bool t = val > v1;                           // strict: first-max tie
            v2 = t ? v1 : fmaxf(v2, val);
            v1 = t ? val : v1;
            m1 = t ? m   : m1;
            q1 = t ? q   : q1;
        }
    }

    // merge 4 lanes (xor 1,2); v1 tie -> smaller q (unsigned: -1 loses)
    #pragma unroll
    for (int off = 1; off <= 2; off <<= 1) {
        float So  = __shfl_xor(S0, off, 64);
        float v1o = __shfl_xor(v1, off, 64);
        float v2o = __shfl_xor(v2, off, 64);
        float m1o = __shfl_xor(m1, off, 64);
        int   q1o = __shfl_xor(q1, off, 64);
        S0 += So;
        bool t = (v1o > v1) || (v1o == v1 && (unsigned)q1o < (unsigned)q1);
        v2 = fmaxf(fminf(v1, v1o), fmaxf(v2, v2o));      // 2nd max of union
        v1 = t ? v1o : v1;
        m1 = t ? m1o : m1;
        q1 = t ? q1o : q1;
    }

    // EXACT fallback when fast top-2 gap can't certify argmax (~0.06% rows):
    // bit-identical chain to the validated R2 kernel (expf + IEEE div).
    if (l == 0 && (v1 - v2) < 5e-5f) {
        float bv = -INFINITY, bm = 0.0f; int bq = -1;
        for (int q = 0; q < Q_; ++q) {
            float x = rowp[q];                 // L1-hot
            float e = expf(-x);
            float m = 1.0f / (1.0f + e);
            float vv = s_msc[q] * m;
            if (vv > bv) { bv = vv; bq = q; bm = m; }
        }
        q1 = bq; m1 = bm;                      // v1/S0 keep fast values (2% tol)
    }

    bool valid = (q1 >= 0) && (s_msc[q1] > -1e29f) &&     // keep[mid]
                 (m1 >= 1e-3f) &&
                 (pad[(size_t)b * P_ + p] == 0);

    float conf = __expf(v1) * __builtin_amdgcn_rcpf(S0);  // 2% tol
    float insf = valid ? (float)q1 : -1.0f;
    if (l == 0 && valid) s_flag[q1] = 1;                  // benign race

    // compact stores: lane t<16 gathers row t's result from its leader lane 4t
    int   src    = (wl & 15) * 4;
    float conf_g = __shfl(conf, src, 64);
    float insf_g = __shfl(insf, src, 64);
    if (wl < 16) {
        int prow = blockIdx.x * 64 + wave * 16 + wl;
        size_t o = (size_t)b * P_ + prow;
        out[o]                       = 0.0f;   // sem: labels[mid]==0 whenever valid
        out[(size_t)B_ * P_ + o]     = insf_g;
        out[2 * (size_t)B_ * P_ + o] = conf_g;
    }

    __syncthreads();
    // replicated flag tables: per-word contention ~3125/NREP ~= 49 blocks
    if (tid < Q_ && s_flag[tid]) {
        int rep = blockIdx.x & (NREP - 1);
        atomicOr(&flags[(b * NREP + rep) * Q_ + tid], 1);
    }
}

// OR-reduce replicas + cumsum -> seg[b][q]
__global__ void pano_pass2(const int* __restrict__ flags,
                           int* __restrict__ seg)
{
    const int b = blockIdx.x, tid = threadIdx.x;
    __shared__ int s_ne[Q_];
    if (tid < Q_) {
        int f = 0;
        for (int r = 0; r < NREP; ++r)
            f |= flags[(b * NREP + r) * Q_ + tid];
        s_ne[tid] = f ? 1 : 0;
    }
    __syncthreads();
    if (tid == 0) {
        int c = 0;
        #pragma unroll
        for (int q = 0; q < Q_; ++q) { c += s_ne[q]; s_ne[q] = c; }
    }
    __syncthreads();
    if (tid < Q_) seg[b * Q_ + tid] = s_ne[tid];
}

__global__ __launch_bounds__(256) void pano_pass3(
    const int* __restrict__ seg,
    float* __restrict__ out)
{
    const int b = blockIdx.y, tid = threadIdx.x;
    __shared__ int s_seg[Q_];
    if (tid < Q_) s_seg[tid] = seg[b * Q_ + tid];
    __syncthreads();

    int p = blockIdx.x * blockDim.x + tid;
    if (p < P_) {
        size_t o = (size_t)B_ * P_ + (size_t)b * P_ + p;
        float f = out[o];
        out[o] = (f >= 0.0f) ? (float)s_seg[(int)f] : 0.0f;
    }
}

extern "C" void kernel_launch(void* const* d_in, const int* in_sizes, int n_in,
                              void* d_out, int out_size, void* d_ws, size_t ws_size,
                              hipStream_t stream) {
    const float* logits = (const float*)d_in[0];
    const float* masks  = (const float*)d_in[1];
    const unsigned char* pad = (const unsigned char*)d_in[2];
    float* out = (float*)d_out;

    int*   flags = (int*)d_ws;                          // [B][NREP][Q_]
    float* mscp  = (float*)((char*)d_ws + 52224);       // [B*Q_]
    int*   seg   = (int*)((char*)d_ws + 53248);         // [B*Q_]

    hipMemsetAsync(d_ws, 0, B_ * NREP * Q_ * sizeof(int), stream);
    pano_prep<<<dim3(B_), dim3(128), 0, stream>>>(logits, mscp);

    dim3 block(256);
    pano_pass1<<<dim3(P_ / 64, B_), block, 0, stream>>>(masks, pad, out, mscp, flags);
    pano_pass2<<<dim3(B_), dim3(128), 0, stream>>>(flags, seg);
    pano_pass3<<<dim3((P_ + 255) / 256, B_), block, 0, stream>>>(seg, out);
}